// Round 1
// baseline (220.785 us; speedup 1.0000x reference)
//
#include <hip/hip_runtime.h>

// GraphAttentionLayer: N=16, Cin=64, T=512, V=64
// Per b = n*T+t:
//   Y[c,v] = sum_u X[c,u]*W[u,v]      (X[c,u] = x[n,c,t,u])
//   f[v] = sum_c Y[c,v]*a1[c]; g[v] = sum_c Y[c,v]*a2[c]
//   att[i,j] = softmax_j over masked lrelu(f_i + g_j)
//   out[n,c,t,v] = sum_j Y[c,j]*att[v,j]

constexpr float ALPHA = 0.2f;
constexpr float NEG_BIG = -9.0e15f;

__global__ __launch_bounds__(256, 3) void gat_kernel(
    const float* __restrict__ x,   // (16,64,512,64)
    const float* __restrict__ A,   // (3,64,64)
    const float* __restrict__ W,   // (64,64)
    const float* __restrict__ a,   // (128,1)
    float* __restrict__ out)       // (16,64,512,64)
{
    __shared__ float Xl[64 * 65];   // X tile; reused for att after phase 1
    __shared__ float Yl[64 * 65];
    __shared__ float Wl[64 * 64];   // unpadded: float4 reads stay 16B-aligned
    __shared__ float al[128];
    __shared__ float fv[64];
    __shared__ float gv[64];

    const int tid = threadIdx.x;
    const int b   = blockIdx.x;
    const int n   = b >> 9;       // T = 512
    const int t   = b & 511;

    // ---- stage W, a ----
    #pragma unroll
    for (int i = 0; i < 16; ++i) Wl[tid + 256 * i] = W[tid + 256 * i];
    if (tid < 128) al[tid] = a[tid];

    // ---- stage X: X[c,v] = x[((n*64+c)*512+t)*64+v] ----
    {
        const int v  = tid & 63;
        const int c0 = tid >> 6;   // 0..3
        const float* xp = x + (((n * 64) * 512 + t) * 64 + v);
        #pragma unroll
        for (int i = 0; i < 16; ++i) {
            const int c = c0 + 4 * i;
            Xl[c * 65 + v] = xp[(size_t)c * (512 * 64)];
        }
    }
    __syncthreads();

    const int tu = tid & 15;   // output col group: v/u = 4*tu..4*tu+3
    const int tc = tid >> 4;   // output row group: c   = 4*tc..4*tc+3

    // ---- Phase 1: Y = X @ W (4x4 register tile per thread) ----
    {
        float acc[4][4] = {};
        #pragma unroll 4
        for (int v = 0; v < 64; ++v) {
            const float4 wv = *(const float4*)&Wl[v * 64 + 4 * tu];
            float xr[4];
            #pragma unroll
            for (int i = 0; i < 4; ++i) xr[i] = Xl[(4 * tc + i) * 65 + v];
            #pragma unroll
            for (int i = 0; i < 4; ++i) {
                acc[i][0] += xr[i] * wv.x;
                acc[i][1] += xr[i] * wv.y;
                acc[i][2] += xr[i] * wv.z;
                acc[i][3] += xr[i] * wv.w;
            }
        }
        #pragma unroll
        for (int i = 0; i < 4; ++i)
            #pragma unroll
            for (int j = 0; j < 4; ++j)
                Yl[(4 * tc + i) * 65 + 4 * tu + j] = acc[i][j];
    }
    __syncthreads();

    // ---- Phase 2: f, g ----
    if (tid < 64) {
        float s = 0.f;
        #pragma unroll 8
        for (int c = 0; c < 64; ++c) s += Yl[c * 65 + tid] * al[c];
        fv[tid] = s;
    } else if (tid < 128) {
        const int u = tid - 64;
        float s = 0.f;
        #pragma unroll 8
        for (int c = 0; c < 64; ++c) s += Yl[c * 65 + u] * al[64 + c];
        gv[u] = s;
    }
    __syncthreads();

    // ---- Phase 3: att rows -> Xl (reuse), row i, lane j ----
    {
        const int lane = tid & 63;
        const int w    = tid >> 6;   // 0..3
        #pragma unroll 2
        for (int k = 0; k < 16; ++k) {
            const int i = w + 4 * k;
            const float s = fv[i] + gv[lane];
            const float e = s > 0.f ? s : ALPHA * s;
            const float asum = A[i * 64 + lane] + A[4096 + i * 64 + lane]
                             + A[8192 + i * 64 + lane];
            const float val = (asum > 0.f) ? e : NEG_BIG;
            float m = val;
            #pragma unroll
            for (int off = 32; off; off >>= 1) m = fmaxf(m, __shfl_xor(m, off, 64));
            const float p = __expf(val - m);
            float sum = p;
            #pragma unroll
            for (int off = 32; off; off >>= 1) sum += __shfl_xor(sum, off, 64);
            Xl[i * 65 + lane] = p / sum;
        }
    }
    __syncthreads();

    // ---- Phase 4: O[c,v] = sum_j Y[c,j]*att[v,j]; store (N,C,T,V) ----
    {
        float acc[4][4] = {};
        #pragma unroll 4
        for (int j = 0; j < 64; ++j) {
            float yr[4], ar[4];
            #pragma unroll
            for (int i = 0; i < 4; ++i) yr[i] = Yl[(4 * tc + i) * 65 + j];
            #pragma unroll
            for (int k = 0; k < 4; ++k) ar[k] = Xl[(4 * tu + k) * 65 + j];
            #pragma unroll
            for (int i = 0; i < 4; ++i)
                #pragma unroll
                for (int k = 0; k < 4; ++k)
                    acc[i][k] += yr[i] * ar[k];
        }
        #pragma unroll
        for (int i = 0; i < 4; ++i) {
            const int c = 4 * tc + i;
            float4 o = make_float4(acc[i][0], acc[i][1], acc[i][2], acc[i][3]);
            *(float4*)&out[(((n * 64 + c) * 512 + t) * 64) + 4 * tu] = o;
        }
    }
}

extern "C" void kernel_launch(void* const* d_in, const int* in_sizes, int n_in,
                              void* d_out, int out_size, void* d_ws, size_t ws_size,
                              hipStream_t stream) {
    const float* x = (const float*)d_in[0];
    const float* A = (const float*)d_in[1];
    const float* W = (const float*)d_in[2];
    const float* a = (const float*)d_in[3];
    float* out = (float*)d_out;
    gat_kernel<<<16 * 512, 256, 0, stream>>>(x, A, W, a, out);
}

// Round 2
// 110.567 us; speedup vs baseline: 1.9969x; 1.9969x over previous
//
#include <hip/hip_runtime.h>

// GraphAttentionLayer: N=16, Cin=64, T=512, V=64. Per b = n*T+t:
//   Y[c,v] = sum_u X[c,u]*W[u,v]           (MFMA bf16, A=X, B^T=Wt)
//   f[v] = sum_c Y[c,v]*a1[c]; g likewise  (fp32 from LDS Y)
//   att[i,j] = softmax_j masked lrelu(f_i + g_j)
//   out[c,v] = sum_j Y[c,j]*att[v,j]       (MFMA bf16, A=Yb, B^T=att rows)

using bf16x8 = __attribute__((ext_vector_type(8))) short;
using f32x4  = __attribute__((ext_vector_type(4))) float;

constexpr float ALPHA   = 0.2f;
constexpr float NEG_BIG = -9.0e15f;

__device__ __forceinline__ unsigned short f2bf(float f) {
    unsigned u = __float_as_uint(f);
    u += 0x7fffu + ((u >> 16) & 1u);   // RNE
    return (unsigned short)(u >> 16);
}

// One-time (per launch): maskbits[i] bit j = (Asum[i][j] > 0)
__global__ void mask_kernel(const float* __restrict__ A,
                            unsigned long long* __restrict__ mask) {
    const int i = threadIdx.x;   // 64 threads
    unsigned long long m = 0;
    for (int j = 0; j < 64; ++j) {
        float s = A[i*64 + j] + A[4096 + i*64 + j] + A[8192 + i*64 + j];
        if (s > 0.f) m |= (1ull << j);
    }
    mask[i] = m;
}

__global__ __launch_bounds__(256, 4) void gat_kernel(
    const float* __restrict__ x,                    // (16,64,512,64)
    const float* __restrict__ a,                    // (128,)
    const unsigned long long* __restrict__ maskbits,// (64,)
    const float* __restrict__ W,                    // (64,64)
    float* __restrict__ out)                        // (16,64,512,64)
{
    // stride 72 bf16 rows: 144 B = 36 words -> 16-lane row-parallel b128 reads
    // hit banks {4r mod 32}: 2-way max (free). 16B alignment kept (k mult of 8).
    __shared__ unsigned short XbYb[64 * 72];  // X (mm1 A) then Yb (mm2 A)
    __shared__ unsigned short WtPb[64 * 72];  // Wt (mm1 B^T) then att (mm2 B^T)
    __shared__ float Yf[64 * 68];             // fp32 Y for f/g
    __shared__ float fv[64], gv[64];

    const int tid  = threadIdx.x;
    const int b    = blockIdx.x;
    const int n    = b >> 9, t = b & 511;
    const int w    = tid >> 6, lane = tid & 63;
    const int fr   = lane & 15;          // fragment row/col
    const int fk   = (lane >> 4) * 8;    // fragment k base (elements)

    // ---- stage X (fp32 -> bf16), rows c, cols u ----
    {
        const int c = tid >> 2, q = tid & 3;
        const float* xp = x + (size_t)n * 2097152 + (size_t)c * 32768 + t * 64 + q * 16;
        float4 v0 = ((const float4*)xp)[0];
        float4 v1 = ((const float4*)xp)[1];
        float4 v2 = ((const float4*)xp)[2];
        float4 v3 = ((const float4*)xp)[3];
        union { bf16x8 v; unsigned short s[8]; } u0, u1;
        u0.s[0]=f2bf(v0.x); u0.s[1]=f2bf(v0.y); u0.s[2]=f2bf(v0.z); u0.s[3]=f2bf(v0.w);
        u0.s[4]=f2bf(v1.x); u0.s[5]=f2bf(v1.y); u0.s[6]=f2bf(v1.z); u0.s[7]=f2bf(v1.w);
        u1.s[0]=f2bf(v2.x); u1.s[1]=f2bf(v2.y); u1.s[2]=f2bf(v2.z); u1.s[3]=f2bf(v2.w);
        u1.s[4]=f2bf(v3.x); u1.s[5]=f2bf(v3.y); u1.s[6]=f2bf(v3.z); u1.s[7]=f2bf(v3.w);
        *(bf16x8*)&XbYb[c * 72 + q * 16]     = u0.v;
        *(bf16x8*)&XbYb[c * 72 + q * 16 + 8] = u1.v;
    }
    // ---- stage W transposed (Wt[v][u] = W[u][v]) ----
    {
        const int u = tid >> 2;
        #pragma unroll
        for (int rep = 0; rep < 4; ++rep) {
            const int c4 = (tid & 3) + 4 * rep;
            float4 wv = *(const float4*)&W[u * 64 + c4 * 4];
            WtPb[(c4 * 4 + 0) * 72 + u] = f2bf(wv.x);
            WtPb[(c4 * 4 + 1) * 72 + u] = f2bf(wv.y);
            WtPb[(c4 * 4 + 2) * 72 + u] = f2bf(wv.z);
            WtPb[(c4 * 4 + 3) * 72 + u] = f2bf(wv.w);
        }
    }
    __syncthreads();

    // ---- mm1: Y = X @ W. wave w owns rows 16w..16w+15, all 4 col-blocks ----
    {
        f32x4 acc[4] = {{0,0,0,0},{0,0,0,0},{0,0,0,0},{0,0,0,0}};
        #pragma unroll
        for (int kc = 0; kc < 2; ++kc) {
            bf16x8 af = *(const bf16x8*)&XbYb[(16 * w + fr) * 72 + 32 * kc + fk];
            #pragma unroll
            for (int cb = 0; cb < 4; ++cb) {
                bf16x8 bf = *(const bf16x8*)&WtPb[(16 * cb + fr) * 72 + 32 * kc + fk];
                acc[cb] = __builtin_amdgcn_mfma_f32_16x16x32_bf16(af, bf, acc[cb], 0, 0, 0);
            }
        }
        // epilogue: Yf fp32 + Yb bf16 (own rows only -> no cross-wave race)
        #pragma unroll
        for (int cb = 0; cb < 4; ++cb)
            #pragma unroll
            for (int r = 0; r < 4; ++r) {
                const int row = 16 * w + (lane >> 4) * 4 + r;
                const int col = 16 * cb + fr;
                const float y = acc[cb][r];
                Yf[row * 68 + col]   = y;
                XbYb[row * 72 + col] = f2bf(y);
            }
    }
    __syncthreads();

    // ---- f, g (fp32) ----
    if (tid < 128) {
        const int v = tid & 63;
        const float* ap = a + (tid >> 6) * 64;
        float s = 0.f;
        #pragma unroll 8
        for (int c = 0; c < 64; ++c) s += Yf[c * 68 + v] * ap[c];
        (tid < 64 ? fv : gv)[v] = s;
    }
    __syncthreads();

    // ---- softmax rows -> att (bf16) into WtPb. wave w rows i = 4k+w ----
    {
        const float gj = gv[lane];
        #pragma unroll 4
        for (int k = 0; k < 16; ++k) {
            const int i = 4 * k + w;
            const float s0 = fv[i] + gj;
            const float e  = fmaxf(s0, ALPHA * s0);       // leaky relu
            const float val = ((maskbits[i] >> lane) & 1ull) ? e : NEG_BIG;
            float m = val;
            #pragma unroll
            for (int off = 32; off; off >>= 1) m = fmaxf(m, __shfl_xor(m, off, 64));
            const float p = __expf(val - m);
            float sum = p;
            #pragma unroll
            for (int off = 32; off; off >>= 1) sum += __shfl_xor(sum, off, 64);
            WtPb[i * 72 + lane] = f2bf(p * __builtin_amdgcn_rcpf(sum));
        }
    }
    __syncthreads();

    // ---- mm2: out[c,v] = sum_j Yb[c,j] * att[v,j] ----
    {
        f32x4 acc[4] = {{0,0,0,0},{0,0,0,0},{0,0,0,0},{0,0,0,0}};
        #pragma unroll
        for (int kc = 0; kc < 2; ++kc) {
            bf16x8 af = *(const bf16x8*)&XbYb[(16 * w + fr) * 72 + 32 * kc + fk];
            #pragma unroll
            for (int cb = 0; cb < 4; ++cb) {
                bf16x8 bf = *(const bf16x8*)&WtPb[(16 * cb + fr) * 72 + 32 * kc + fk];
                acc[cb] = __builtin_amdgcn_mfma_f32_16x16x32_bf16(af, bf, acc[cb], 0, 0, 0);
            }
        }
        float* op = out + (size_t)n * 2097152 + t * 64;
        #pragma unroll
        for (int cb = 0; cb < 4; ++cb)
            #pragma unroll
            for (int r = 0; r < 4; ++r) {
                const int row = 16 * w + (lane >> 4) * 4 + r;   // c
                const int col = 16 * cb + fr;                   // v
                op[(size_t)row * 32768 + col] = acc[cb][r];
            }
    }
}

extern "C" void kernel_launch(void* const* d_in, const int* in_sizes, int n_in,
                              void* d_out, int out_size, void* d_ws, size_t ws_size,
                              hipStream_t stream) {
    const float* x = (const float*)d_in[0];
    const float* A = (const float*)d_in[1];
    const float* W = (const float*)d_in[2];
    const float* a = (const float*)d_in[3];
    float* out = (float*)d_out;
    unsigned long long* mask = (unsigned long long*)d_ws;

    mask_kernel<<<1, 64, 0, stream>>>(A, mask);
    gat_kernel<<<16 * 512, 256, 0, stream>>>(x, a, mask, W, out);
}

// Round 3
// 54.560 us; speedup vs baseline: 4.0466x; 2.0265x over previous
//
#include <hip/hip_runtime.h>
#include <hip/hip_bf16.h>

// GraphAttentionLayer: N=16, Cin=64, T=512, V=64. Per b = n*T+t:
//   Y[c,v] = sum_u X[c,u]*W[u,v]                    (MFMA bf16)
//   f[v] = sum_c Y[c,v]*a1[c]; g likewise           (from mm1 accumulators)
//   p[i,j] = mask ? exp(lrelu(f_i+g_j)) : 0         (UNNORMALIZED, no reductions)
//   out[c,v] = (sum_j Y[c,j]*p[v,j]) / S_v          (MFMA; S_v via ones-MFMA)

using bf16x8 = __attribute__((ext_vector_type(8))) short;
using f32x4  = __attribute__((ext_vector_type(4))) float;

constexpr float ALPHA = 0.2f;

__device__ __forceinline__ unsigned short f2bf(float f) {
    union { __hip_bfloat16 h; unsigned short s; } u;
    u.h = __float2bfloat16(f);
    return u.s;
}

// One-time: maskbits[i] bit j = (Asum[i][j] > 0)
__global__ void mask_kernel(const float* __restrict__ A,
                            unsigned long long* __restrict__ mask) {
    const int i = threadIdx.x;   // 64 threads
    unsigned long long m = 0;
    for (int j = 0; j < 64; ++j) {
        float s = A[i*64 + j] + A[4096 + i*64 + j] + A[8192 + i*64 + j];
        if (s > 0.f) m |= (1ull << j);
    }
    mask[i] = m;
}

__global__ __launch_bounds__(256, 6) void gat_kernel(
    const float* __restrict__ x,                    // (16,64,512,64)
    const float* __restrict__ a,                    // (128,)
    const unsigned long long* __restrict__ maskbits,// (64,)
    const float* __restrict__ W,                    // (64,64)
    float* __restrict__ out)                        // (16,64,512,64)
{
    // stride-72 bf16 rows (144 B): row-parallel b128 reads are <=2-way on banks
    __shared__ unsigned short XbYb[64 * 72];  // X (mm1 A) then Yb (mm2 A)
    __shared__ unsigned short WtPb[64 * 72];  // Wt (mm1 B^T) then P (mm2 B^T)
    __shared__ float al[128];
    __shared__ float fpart[4][64];
    __shared__ float gpart[4][64];
    __shared__ unsigned long long ml[64];

    const int tid  = threadIdx.x;
    const int b    = blockIdx.x;
    const int n    = b >> 9, t = b & 511;
    const int w    = tid >> 6, lane = tid & 63;
    const int fr   = lane & 15;        // fragment row/col
    const int hi   = lane >> 4;        // 0..3
    const int fk   = hi * 8;           // fragment k base

    // ---- stage X (fp32 -> bf16) ----
    {
        const int c = tid >> 2, q = tid & 3;
        const float* xp = x + (size_t)n * 2097152 + (size_t)c * 32768 + (size_t)t * 64 + q * 16;
        float4 v0 = ((const float4*)xp)[0];
        float4 v1 = ((const float4*)xp)[1];
        float4 v2 = ((const float4*)xp)[2];
        float4 v3 = ((const float4*)xp)[3];
        union { bf16x8 v; unsigned short s[8]; } u0, u1;
        u0.s[0]=f2bf(v0.x); u0.s[1]=f2bf(v0.y); u0.s[2]=f2bf(v0.z); u0.s[3]=f2bf(v0.w);
        u0.s[4]=f2bf(v1.x); u0.s[5]=f2bf(v1.y); u0.s[6]=f2bf(v1.z); u0.s[7]=f2bf(v1.w);
        u1.s[0]=f2bf(v2.x); u1.s[1]=f2bf(v2.y); u1.s[2]=f2bf(v2.z); u1.s[3]=f2bf(v2.w);
        u1.s[4]=f2bf(v3.x); u1.s[5]=f2bf(v3.y); u1.s[6]=f2bf(v3.z); u1.s[7]=f2bf(v3.w);
        *(bf16x8*)&XbYb[c * 72 + q * 16]     = u0.v;
        *(bf16x8*)&XbYb[c * 72 + q * 16 + 8] = u1.v;
    }
    // ---- stage W transposed ----
    {
        const int u = tid >> 2;
        #pragma unroll
        for (int rep = 0; rep < 4; ++rep) {
            const int c4 = (tid & 3) + 4 * rep;
            float4 wv = *(const float4*)&W[u * 64 + c4 * 4];
            WtPb[(c4 * 4 + 0) * 72 + u] = f2bf(wv.x);
            WtPb[(c4 * 4 + 1) * 72 + u] = f2bf(wv.y);
            WtPb[(c4 * 4 + 2) * 72 + u] = f2bf(wv.z);
            WtPb[(c4 * 4 + 3) * 72 + u] = f2bf(wv.w);
        }
    }
    if (tid < 128) al[tid] = a[tid];
    if (tid >= 192) ml[tid - 192] = maskbits[tid - 192];
    __syncthreads();

    // ---- mm1: Y = X @ W; epilogue: Yb (bf16) + f/g partials from acc ----
    {
        f32x4 acc[4] = {{0,0,0,0},{0,0,0,0},{0,0,0,0},{0,0,0,0}};
        #pragma unroll
        for (int kc = 0; kc < 2; ++kc) {
            bf16x8 af = *(const bf16x8*)&XbYb[(16 * w + fr) * 72 + 32 * kc + fk];
            #pragma unroll
            for (int cb = 0; cb < 4; ++cb) {
                bf16x8 bfr = *(const bf16x8*)&WtPb[(16 * cb + fr) * 72 + 32 * kc + fk];
                acc[cb] = __builtin_amdgcn_mfma_f32_16x16x32_bf16(af, bfr, acc[cb], 0, 0, 0);
            }
        }
        float a1r[4], a2r[4];
        #pragma unroll
        for (int r = 0; r < 4; ++r) {
            a1r[r] = al[16 * w + 4 * hi + r];
            a2r[r] = al[64 + 16 * w + 4 * hi + r];
        }
        #pragma unroll
        for (int cb = 0; cb < 4; ++cb) {
            #pragma unroll
            for (int r = 0; r < 4; ++r)
                XbYb[(16 * w + 4 * hi + r) * 72 + 16 * cb + fr] = f2bf(acc[cb][r]);
            float F = acc[cb][0]*a1r[0] + acc[cb][1]*a1r[1] + acc[cb][2]*a1r[2] + acc[cb][3]*a1r[3];
            float G = acc[cb][0]*a2r[0] + acc[cb][1]*a2r[1] + acc[cb][2]*a2r[2] + acc[cb][3]*a2r[3];
            F += __shfl_xor(F, 16, 64); F += __shfl_xor(F, 32, 64);
            G += __shfl_xor(G, 16, 64); G += __shfl_xor(G, 32, 64);
            if (lane < 16) {
                fpart[w][16 * cb + lane] = F;
                gpart[w][16 * cb + lane] = G;
            }
        }
    }
    __syncthreads();

    // ---- unnormalized masked exp(lrelu(f_i+g_j)) -> P (bf16), no reductions ----
    {
        const float gj = (gpart[0][lane] + gpart[1][lane]) + (gpart[2][lane] + gpart[3][lane]);
        #pragma unroll 4
        for (int k = 0; k < 16; ++k) {
            const int i = 4 * k + w;
            const unsigned long long mi = ml[i];
            const float fi = (fpart[0][i] + fpart[1][i]) + (fpart[2][i] + fpart[3][i]);
            const float s0 = fi + gj;
            const float e  = fmaxf(s0, ALPHA * s0);
            // all-zero mask row: reference softmax(all -inf) = uniform -> p=1
            float p;
            if (mi == 0ull) p = 1.0f;
            else            p = ((mi >> lane) & 1ull) ? __expf(e) : 0.0f;
            WtPb[i * 72 + lane] = f2bf(p);
        }
    }
    __syncthreads();

    // ---- mm2: out[c,v] = (sum_j Yb[c,j]*P[v,j]) * rcp(S_v); S via ones-MFMA ----
    {
        f32x4 acc2[4] = {{0,0,0,0},{0,0,0,0},{0,0,0,0},{0,0,0,0}};
        f32x4 accS[4] = {{0,0,0,0},{0,0,0,0},{0,0,0,0},{0,0,0,0}};
        union { bf16x8 v; unsigned short s[8]; } ones;
        #pragma unroll
        for (int j = 0; j < 8; ++j) ones.s[j] = 0x3f80;   // bf16 1.0
        #pragma unroll
        for (int kc = 0; kc < 2; ++kc) {
            bf16x8 af = *(const bf16x8*)&XbYb[(16 * w + fr) * 72 + 32 * kc + fk];
            #pragma unroll
            for (int cb = 0; cb < 4; ++cb) {
                bf16x8 bfr = *(const bf16x8*)&WtPb[(16 * cb + fr) * 72 + 32 * kc + fk];
                acc2[cb] = __builtin_amdgcn_mfma_f32_16x16x32_bf16(af, bfr, acc2[cb], 0, 0, 0);
                accS[cb] = __builtin_amdgcn_mfma_f32_16x16x32_bf16(ones.v, bfr, accS[cb], 0, 0, 0);
            }
        }
        float* op = out + (size_t)n * 2097152 + (size_t)t * 64;
        #pragma unroll
        for (int cb = 0; cb < 4; ++cb) {
            const float rs  = __builtin_amdgcn_rcpf(accS[cb][0]);
            const int   col = 16 * cb + fr;
            #pragma unroll
            for (int r = 0; r < 4; ++r) {
                const int row = 16 * w + 4 * hi + r;
                op[(size_t)row * 32768 + col] = acc2[cb][r] * rs;
            }
        }
    }
}

extern "C" void kernel_launch(void* const* d_in, const int* in_sizes, int n_in,
                              void* d_out, int out_size, void* d_ws, size_t ws_size,
                              hipStream_t stream) {
    const float* x = (const float*)d_in[0];
    const float* A = (const float*)d_in[1];
    const float* W = (const float*)d_in[2];
    const float* a = (const float*)d_in[3];
    float* out = (float*)d_out;
    unsigned long long* mask = (unsigned long long*)d_ws;

    mask_kernel<<<1, 64, 0, stream>>>(A, mask);
    gat_kernel<<<16 * 512, 256, 0, stream>>>(x, a, mask, W, out);
}